// Round 1
// baseline (475.019 us; speedup 1.0000x reference)
//
#include <hip/hip_runtime.h>
#include <hip/hip_bf16.h>

// Problem constants
#define B_    2
#define G_    16
#define N_    4096      // targets per segment
#define S_    1024      // sources per segment
#define D1_   128
#define D2_   256
#define CIN_  384
#define BG_   32        // B_*G_
#define GN_   65536     // G_*N_
#define GS_   16384     // G_*S_

typedef unsigned int u32;
typedef unsigned short u16;
typedef short bf16x8 __attribute__((ext_vector_type(8)));
typedef float f32x4 __attribute__((ext_vector_type(4)));

__device__ __forceinline__ float bf2f(u16 u) {
  union { float f; u32 v; } cv; cv.v = ((u32)u) << 16; return cv.f;
}
__device__ __forceinline__ u16 f2bf(float f) {
  union { __hip_bfloat16 h; u16 u; } cv; cv.h = __float2bfloat16(f); return cv.u;
}
__device__ __forceinline__ void g2l16(const u16* g, u16* l) {
  __builtin_amdgcn_global_load_lds((const __attribute__((address_space(1))) u32*)g,
                                   (__attribute__((address_space(3))) u32*)l, 16, 0, 0);
}

// ---------------- workspace layout (bytes) ----------------
#define OFF_W1BF   0u           // 256*384*2  = 196608
#define OFF_W2BF   196608u      // 256*256*2  = 131072
#define OFF_XYZ2P  327680u      // 32*256*4*16 = 524288
#define OFF_SUM1   851968u      // 16*256*4 = 16384
#define OFF_SQ1    868352u
#define OFF_SUM2   884736u
#define OFF_SQ2    901120u
#define OFF_SS1    917504u      // 16*256*8 = 32768
#define OFF_SS2    950272u
#define OFF_KNNW   983040u      // 32*4096*16 = 2097152
#define OFF_KNNI   3080192u     // 2097152
#define OFF_P2T    5177344u     // 32*1024*256*2 = 16777216
#define OFF_H0     21954560u    // 32*4096*384*2 = 100663296  (H1 aliases this)
#define OFF_Y1     122617856u   // 32*4096*256*2 = 67108864
// total = 189726720 bytes (~181 MB)

// ---------------- prep: convert weights, zero stats, pack xyz2 ----------------
__launch_bounds__(256)
__global__ void prep_kernel(const float* __restrict__ W1, const float* __restrict__ W2,
                            const float* __restrict__ xyz2,
                            u16* __restrict__ W1bf, u16* __restrict__ W2bf,
                            float4* __restrict__ xyz2p, float* __restrict__ zeros)
{
  int idx = blockIdx.x * 256 + threadIdx.x;
  if (idx < 98304) { W1bf[idx] = f2bf(W1[idx]); return; }
  idx -= 98304;
  if (idx < 65536) { W2bf[idx] = f2bf(W2[idx]); return; }
  idx -= 65536;
  if (idx < 16384) { zeros[idx] = 0.f; return; }
  idx -= 16384;
  // idx in [0,8192): (bg, q) source quad
  int bg = idx >> 8, q = idx & 255;
  int b = bg >> 4, g = bg & 15;
  const float* base = xyz2 + (size_t)b * 3 * GS_ + (size_t)g * S_ + q * 4;
  float4 X = *(const float4*)(base);
  float4 Y = *(const float4*)(base + GS_);
  float4 Z = *(const float4*)(base + 2 * GS_);
  float4 M;
  M.x = X.x*X.x + Y.x*Y.x + Z.x*Z.x;
  M.y = X.y*X.y + Y.y*Y.y + Z.y*Z.y;
  M.z = X.z*X.z + Y.z*Y.z + Z.z*Z.z;
  M.w = X.w*X.w + Y.w*Y.w + Z.w*Z.w;
  float4* dst = xyz2p + (size_t)idx * 4;
  dst[0] = X; dst[1] = Y; dst[2] = Z; dst[3] = M;
}

// ---------------- transpose points2 [c][s] f32 -> p2T [s][c] bf16 ----------------
__launch_bounds__(256)
__global__ void t2_kernel(const float* __restrict__ p2, u16* __restrict__ p2T)
{
  __shared__ float tl[64][65];
  int bx = blockIdx.x;
  int bg = bx >> 6, r = bx & 63;
  int ct = r >> 4, st = r & 15;
  int c0 = ct * 64, s0 = st * 64;
  int b = bg >> 4, g = bg & 15;
  int t = threadIdx.x, lane = t & 63, w = t >> 6;
  const float* src = p2 + (size_t)b * D2_ * GS_ + (size_t)g * S_ + s0 + lane;
  #pragma unroll
  for (int i = 0; i < 16; i++) {
    int row = w * 16 + i;
    tl[row][lane] = src[(size_t)(c0 + row) * GS_];
  }
  __syncthreads();
  int cp = t & 31, sr = t >> 5;
  #pragma unroll
  for (int i = 0; i < 8; i++) {
    int sl = sr * 8 + i;
    u32 v = (u32)f2bf(tl[2 * cp][sl]) | ((u32)f2bf(tl[2 * cp + 1][sl]) << 16);
    *(u32*)(p2T + (((size_t)bg * 1024 + s0 + sl) * 256 + c0 + 2 * cp)) = v;
  }
}

// ---------------- kNN: top-3 nearest sources per target ----------------
__launch_bounds__(256)
__global__ void knn_kernel(const float* __restrict__ xyz1, const float4* __restrict__ xyz2p,
                           float4* __restrict__ knnw, int4* __restrict__ knni)
{
  int bx = blockIdx.x;
  int bg = bx >> 4;
  int b = bg >> 4, g = bg & 15;
  int n = (bx & 15) * 256 + threadIdx.x;
  const float* x1b = xyz1 + (size_t)b * 3 * GN_ + (size_t)g * N_ + n;
  float x = x1b[0], y = x1b[GN_], z = x1b[2 * GN_];
  const float4* xp = xyz2p + (size_t)bg * 1024;
  float d0 = 3.4e38f, d1 = 3.4e38f, d2 = 3.4e38f;
  int i0 = 0, i1 = 0, i2 = 0;
  for (int q = 0; q < 256; q++) {
    float4 X = xp[q * 4 + 0], Y = xp[q * 4 + 1], Z = xp[q * 4 + 2], M = xp[q * 4 + 3];
    const float* Xa = (const float*)&X;
    const float* Ya = (const float*)&Y;
    const float* Za = (const float*)&Z;
    const float* Ma = (const float*)&M;
    #pragma unroll
    for (int u = 0; u < 4; u++) {
      float cr = x * Xa[u];
      cr = fmaf(y, Ya[u], cr);
      cr = fmaf(z, Za[u], cr);
      float d = fmaf(-2.f, cr, Ma[u]);
      int s = q * 4 + u;
      bool c2 = d < d2, c1 = d < d1, c0 = d < d0;
      d2 = c1 ? d1 : (c2 ? d : d2);  i2 = c1 ? i1 : (c2 ? s : i2);
      d1 = c0 ? d0 : (c1 ? d : d1);  i1 = c0 ? i0 : (c1 ? s : i1);
      d0 = c0 ? d : d0;              i0 = c0 ? s : i0;
    }
  }
  float m1 = x * x + y * y + z * z;
  // true squared distance; clamp to 0 (cancellation can go slightly negative)
  float t0 = fmaxf(d0 + m1, 0.f), t1 = fmaxf(d1 + m1, 0.f), t2v = fmaxf(d2 + m1, 0.f);
  float w0 = 1.f / (t0 + 1e-8f);
  float w1 = 1.f / (t1 + 1e-8f);
  float w2 = 1.f / (t2v + 1e-8f);
  float inv = 1.f / (w0 + w1 + w2);
  size_t gi = (size_t)bg * 4096 + n;
  knnw[gi] = make_float4(w0 * inv, w1 * inv, w2 * inv, 0.f);
  knni[gi] = make_int4(i0, i1, i2, 0);
}

// ---------------- interp + concat -> H0 [bg][n][384] bf16 ----------------
__device__ __forceinline__ float bfq(uint4 q, int i) {
  u32 w = (i < 2) ? ((i & 1) ? q.x >> 16 : (q.x & 0xffffu))
        : (i < 4) ? ((i & 1) ? q.y >> 16 : (q.y & 0xffffu))
        : (i < 6) ? ((i & 1) ? q.z >> 16 : (q.z & 0xffffu))
                  : ((i & 1) ? q.w >> 16 : (q.w & 0xffffu));
  return bf2f((u16)w);
}

__launch_bounds__(256)
__global__ void interp_kernel(const float* __restrict__ points1, const u16* __restrict__ p2T,
                              const float4* __restrict__ knnw, const int4* __restrict__ knni,
                              u16* __restrict__ H0)
{
  int bx = blockIdx.x;
  int bg = bx >> 6, n0 = (bx & 63) * 64;
  int b = bg >> 4, g = bg & 15;
  int t = threadIdx.x;
  int pt = t & 63;
  size_t gi = (size_t)bg * 4096 + n0 + pt;
  float4 wv = knnw[gi];
  int4 iv = knni[gi];
  const u16* r0 = p2T + ((size_t)bg * 1024 + iv.x) * 256;
  const u16* r1 = p2T + ((size_t)bg * 1024 + iv.y) * 256;
  const u16* r2 = p2T + ((size_t)bg * 1024 + iv.z) * 256;
  const float* p1b = points1 + (size_t)b * D1_ * GN_ + (size_t)g * N_ + n0 + pt;
  u16* h0row = H0 + gi * 384;
  for (int it = 0; it < 12; it++) {
    int chunk = (t >> 6) + 4 * it;   // wave-uniform, 0..47
    int c0 = chunk * 8;
    float v[8];
    if (chunk < 16) {
      #pragma unroll
      for (int i = 0; i < 8; i++) v[i] = p1b[(size_t)(c0 + i) * GN_];
    } else {
      int cc = c0 - 128;
      uint4 A = *(const uint4*)(r0 + cc);
      uint4 Bv = *(const uint4*)(r1 + cc);
      uint4 C = *(const uint4*)(r2 + cc);
      #pragma unroll
      for (int i = 0; i < 8; i++)
        v[i] = wv.x * bfq(A, i) + wv.y * bfq(Bv, i) + wv.z * bfq(C, i);
    }
    uint4 o;
    o.x = (u32)f2bf(v[0]) | ((u32)f2bf(v[1]) << 16);
    o.y = (u32)f2bf(v[2]) | ((u32)f2bf(v[3]) << 16);
    o.z = (u32)f2bf(v[4]) | ((u32)f2bf(v[5]) << 16);
    o.w = (u32)f2bf(v[6]) | ((u32)f2bf(v[7]) << 16);
    *(uint4*)(h0row + c0) = o;
  }
}

// ---------------- GEMM: Y[m][n] = W[m][k] * Bm[n][k]^T + bias, per segment ----------------
// block: 256 thr = 4 waves; tile M=256 x N=64; K-step 32; m97-style global_load_lds staging.
template<int K, bool FINAL>
__launch_bounds__(256)
__global__ void gemm_kernel(const u16* __restrict__ A, const u16* __restrict__ Bm,
                            const float* __restrict__ bias,
                            float* __restrict__ sumw, float* __restrict__ sqw,
                            u16* __restrict__ Y, float* __restrict__ Out)
{
  __shared__ u16 As[256 * 32];
  __shared__ u16 Bs[64 * 32];
  int bx = blockIdx.x;
  int bg = bx >> 6, nt = bx & 63;
  int b = bg >> 4, g = bg & 15;
  int n0 = nt * 64;
  int t = threadIdx.x;
  int wid = t >> 6, l = t & 63;
  int llo = l & 15, lhi = l >> 4;
  const u16* Bbase = Bm + ((size_t)bg * 4096 + n0) * K;

  f32x4 acc[4][4];
  #pragma unroll
  for (int i = 0; i < 4; i++)
    #pragma unroll
    for (int j = 0; j < 4; j++) acc[i][j] = (f32x4)0.f;

  for (int k0 = 0; k0 < K; k0 += 32) {
    // stage A tile: 256 rows x 32 k (16 KB) — 4 lds-loads per wave
    #pragma unroll
    for (int q = 0; q < 4; q++) {
      int idx = (wid * 4 + q) * 64 + l;
      int row = idx >> 2, c16 = idx & 3;
      g2l16(A + (size_t)row * K + k0 + c16 * 8, As + (size_t)(wid * 4 + q) * 512);
    }
    // stage B tile: 64 rows x 32 k (4 KB) — 1 per wave
    {
      int idx = wid * 64 + l;
      int row = idx >> 2, c16 = idx & 3;
      g2l16(Bbase + (size_t)row * K + k0 + c16 * 8, Bs + (size_t)wid * 512);
    }
    __syncthreads();
    bf16x8 af[4], bf[4];
    #pragma unroll
    for (int i = 0; i < 4; i++)
      af[i] = *(const bf16x8*)(As + (wid * 64 + i * 16 + llo) * 32 + lhi * 8);
    #pragma unroll
    for (int j = 0; j < 4; j++)
      bf[j] = *(const bf16x8*)(Bs + (j * 16 + llo) * 32 + lhi * 8);
    #pragma unroll
    for (int i = 0; i < 4; i++)
      #pragma unroll
      for (int j = 0; j < 4; j++)
        acc[i][j] = __builtin_amdgcn_mfma_f32_16x16x32_bf16(af[i], bf[j], acc[i][j], 0, 0, 0);
    __syncthreads();
  }

  int m_base = wid * 64;
  // bias + per-channel stats (sum, sumsq over this block's 64 n)
  #pragma unroll
  for (int i = 0; i < 4; i++) {
    #pragma unroll
    for (int r = 0; r < 4; r++) {
      int m = m_base + i * 16 + lhi * 4 + r;
      float bv = bias[m];
      float s = 0.f, ss = 0.f;
      #pragma unroll
      for (int j = 0; j < 4; j++) {
        float v = acc[i][j][r] + bv;
        acc[i][j][r] = v;
        s += v; ss += v * v;
      }
      #pragma unroll
      for (int off = 1; off < 16; off <<= 1) {
        s += __shfl_xor(s, off, 64);
        ss += __shfl_xor(ss, off, 64);
      }
      if (llo == 0) {
        atomicAdd(&sumw[g * 256 + m], s);
        atomicAdd(&sqw[g * 256 + m], ss);
      }
    }
  }
  if (FINAL) {
    // write f32 pre-BN into d_out layout [b][m][g*4096+n] (coalesced over llo)
    #pragma unroll
    for (int i = 0; i < 4; i++)
      #pragma unroll
      for (int r = 0; r < 4; r++) {
        int m = m_base + i * 16 + lhi * 4 + r;
        size_t rowb = ((size_t)b * 256 + m) * 65536 + (size_t)g * 4096 + n0;
        #pragma unroll
        for (int j = 0; j < 4; j++)
          Out[rowb + j * 16 + llo] = acc[i][j][r];
      }
  } else {
    // write bf16 Y1 layout [bg*4096+n][m] (k-contiguous for next GEMM)
    #pragma unroll
    for (int i = 0; i < 4; i++)
      #pragma unroll
      for (int j = 0; j < 4; j++) {
        u32 lo = (u32)f2bf(acc[i][j][0]) | ((u32)f2bf(acc[i][j][1]) << 16);
        u32 hi = (u32)f2bf(acc[i][j][2]) | ((u32)f2bf(acc[i][j][3]) << 16);
        size_t addr = ((size_t)bg * 4096 + n0 + j * 16 + llo) * 256 + m_base + i * 16 + lhi * 4;
        uint2 pv; pv.x = lo; pv.y = hi;
        *(uint2*)(Y + addr) = pv;
      }
  }
}

// ---------------- BN finalize: (sum,sumsq) -> (scale,shift) ----------------
__global__ void bnfin_kernel(const float* __restrict__ sum, const float* __restrict__ sq,
                             const float* __restrict__ gamma, const float* __restrict__ beta,
                             float2* __restrict__ ss)
{
  int g = blockIdx.x, m = threadIdx.x;
  int i = g * 256 + m;
  float mean = sum[i] * (1.f / 8192.f);
  float var = sq[i] * (1.f / 8192.f) - mean * mean;
  var = fmaxf(var, 0.f);
  float rstd = rsqrtf(var + 1e-5f);
  float sc = gamma[m] * rstd;
  ss[i] = make_float2(sc, beta[m] - mean * sc);
}

// ---------------- BN apply 1: H1 = relu(bn(Y1)) bf16 ----------------
__launch_bounds__(256)
__global__ void bnapply1_kernel(const u16* __restrict__ Y1, const float2* __restrict__ ss,
                                u16* __restrict__ H1)
{
  int f8 = blockIdx.x * 256 + threadIdx.x;      // 0..4194303
  int m8 = (f8 & 31) * 8;
  int row = f8 >> 5;
  int g = (row >> 12) & 15;
  uint4 yv = *(const uint4*)(Y1 + (size_t)f8 * 8);
  const float2* sb = ss + g * 256 + m8;
  const u32* yw = (const u32*)&yv;
  uint4 o;
  u32* ow = (u32*)&o;
  #pragma unroll
  for (int i = 0; i < 4; i++) {
    u32 w = yw[i];
    float2 s0 = sb[2 * i], s1 = sb[2 * i + 1];
    float a = fmaxf(fmaf(bf2f((u16)(w & 0xffffu)), s0.x, s0.y), 0.f);
    float c = fmaxf(fmaf(bf2f((u16)(w >> 16)), s1.x, s1.y), 0.f);
    ow[i] = (u32)f2bf(a) | ((u32)f2bf(c) << 16);
  }
  *(uint4*)(H1 + (size_t)f8 * 8) = o;
}

// ---------------- BN apply 2: in-place on d_out f32 ----------------
__launch_bounds__(256)
__global__ void bnapply2_kernel(float* __restrict__ Out, const float2* __restrict__ ss)
{
  int f8 = blockIdx.x * 256 + threadIdx.x;
  size_t base = (size_t)f8 * 8;
  int m = (int)((base >> 16) & 255);
  int g = (int)((base >> 12) & 15);
  float2 sc = ss[g * 256 + m];
  float4 a = *(float4*)(Out + base);
  float4 b4 = *(float4*)(Out + base + 4);
  a.x = fmaxf(fmaf(a.x, sc.x, sc.y), 0.f);
  a.y = fmaxf(fmaf(a.y, sc.x, sc.y), 0.f);
  a.z = fmaxf(fmaf(a.z, sc.x, sc.y), 0.f);
  a.w = fmaxf(fmaf(a.w, sc.x, sc.y), 0.f);
  b4.x = fmaxf(fmaf(b4.x, sc.x, sc.y), 0.f);
  b4.y = fmaxf(fmaf(b4.y, sc.x, sc.y), 0.f);
  b4.z = fmaxf(fmaf(b4.z, sc.x, sc.y), 0.f);
  b4.w = fmaxf(fmaf(b4.w, sc.x, sc.y), 0.f);
  *(float4*)(Out + base) = a;
  *(float4*)(Out + base + 4) = b4;
}

// ---------------- launch ----------------
extern "C" void kernel_launch(void* const* d_in, const int* in_sizes, int n_in,
                              void* d_out, int out_size, void* d_ws, size_t ws_size,
                              hipStream_t stream)
{
  (void)in_sizes; (void)n_in; (void)out_size; (void)ws_size;
  const float* xyz1    = (const float*)d_in[0];
  const float* points1 = (const float*)d_in[1];
  const float* xyz2    = (const float*)d_in[3];
  const float* points2 = (const float*)d_in[4];
  const float* W1      = (const float*)d_in[6];
  const float* b1      = (const float*)d_in[7];
  const float* gamma1  = (const float*)d_in[8];
  const float* beta1   = (const float*)d_in[9];
  const float* W2      = (const float*)d_in[10];
  const float* b2      = (const float*)d_in[11];
  const float* gamma2  = (const float*)d_in[12];
  const float* beta2   = (const float*)d_in[13];
  float* out = (float*)d_out;
  char* ws = (char*)d_ws;

  u16*    W1bf  = (u16*)(ws + OFF_W1BF);
  u16*    W2bf  = (u16*)(ws + OFF_W2BF);
  float4* xyz2p = (float4*)(ws + OFF_XYZ2P);
  float*  sum1  = (float*)(ws + OFF_SUM1);
  float*  sq1   = (float*)(ws + OFF_SQ1);
  float*  sum2  = (float*)(ws + OFF_SUM2);
  float*  sq2   = (float*)(ws + OFF_SQ2);
  float2* ss1   = (float2*)(ws + OFF_SS1);
  float2* ss2   = (float2*)(ws + OFF_SS2);
  float4* knnw  = (float4*)(ws + OFF_KNNW);
  int4*   knni  = (int4*)(ws + OFF_KNNI);
  u16*    p2T   = (u16*)(ws + OFF_P2T);
  u16*    H0    = (u16*)(ws + OFF_H0);   // H1 aliases H0 after GEMM1
  u16*    Y1    = (u16*)(ws + OFF_Y1);

  prep_kernel<<<736, 256, 0, stream>>>(W1, W2, xyz2, W1bf, W2bf, xyz2p, sum1);
  t2_kernel<<<2048, 256, 0, stream>>>(points2, p2T);
  knn_kernel<<<512, 256, 0, stream>>>(xyz1, xyz2p, knnw, knni);
  interp_kernel<<<2048, 256, 0, stream>>>(points1, p2T, knnw, knni, H0);
  gemm_kernel<384, false><<<2048, 256, 0, stream>>>(W1bf, H0, b1, sum1, sq1, Y1, nullptr);
  bnfin_kernel<<<16, 256, 0, stream>>>(sum1, sq1, gamma1, beta1, ss1);
  bnapply1_kernel<<<16384, 256, 0, stream>>>(Y1, ss1, H0 /* H1 alias */);
  gemm_kernel<256, true><<<2048, 256, 0, stream>>>(W2bf, H0, b2, sum2, sq2, nullptr, out);
  bnfin_kernel<<<16, 256, 0, stream>>>(sum2, sq2, gamma2, beta2, ss2);
  bnapply2_kernel<<<16384, 256, 0, stream>>>(out, ss2);
}

// Round 2
// 340.904 us; speedup vs baseline: 1.3934x; 1.3934x over previous
//
#include <hip/hip_runtime.h>
#include <hip/hip_bf16.h>

// Problem constants
#define B_    2
#define G_    16
#define N_    4096      // targets per segment
#define S_    1024      // sources per segment
#define D1_   128
#define D2_   256
#define CIN_  384
#define BG_   32        // B_*G_
#define GN_   65536     // G_*N_
#define GS_   16384     // G_*S_

typedef unsigned int u32;
typedef unsigned short u16;
typedef short bf16x8 __attribute__((ext_vector_type(8)));
typedef float f32x4 __attribute__((ext_vector_type(4)));

__device__ __forceinline__ float bf2f(u16 u) {
  union { float f; u32 v; } cv; cv.v = ((u32)u) << 16; return cv.f;
}
__device__ __forceinline__ u16 f2bf(float f) {
  union { __hip_bfloat16 h; u16 u; } cv; cv.h = __float2bfloat16(f); return cv.u;
}
__device__ __forceinline__ void g2l16(const u16* g, u16* l) {
  __builtin_amdgcn_global_load_lds((const __attribute__((address_space(1))) u32*)g,
                                   (__attribute__((address_space(3))) u32*)l, 16, 0, 0);
}

// ---------------- workspace layout (bytes) ----------------
#define OFF_W1BF   0u           // 256*384*2  = 196608
#define OFF_W2BF   196608u      // 256*256*2  = 131072
#define OFF_XYZ2P  327680u      // 32*256*4*16 = 524288
#define OFF_SUM1   851968u      // 16*256*4 = 16384
#define OFF_SQ1    868352u
#define OFF_SUM2   884736u
#define OFF_SQ2    901120u
#define OFF_SS1    917504u      // 16*256*8 = 32768
#define OFF_SS2    950272u
#define OFF_KNNW   983040u      // 32*4096*16 = 2097152
#define OFF_KNNI   3080192u     // 2097152
#define OFF_P2T    5177344u     // 32*1024*256*2 = 16777216
#define OFF_Y2     21954560u    // 32*4096*256*2 = 67108864  (bf16 pre-BN2 in OUT layout)
#define OFF_Y1     122617856u   // 32*4096*256*2 = 67108864  (bf16 pre-BN1, [n][256])

// ---------------- prep: convert weights, zero stats, pack xyz2 ----------------
__launch_bounds__(256)
__global__ void prep_kernel(const float* __restrict__ W1, const float* __restrict__ W2,
                            const float* __restrict__ xyz2,
                            u16* __restrict__ W1bf, u16* __restrict__ W2bf,
                            float4* __restrict__ xyz2p, float* __restrict__ zeros)
{
  int idx = blockIdx.x * 256 + threadIdx.x;
  if (idx < 98304) { W1bf[idx] = f2bf(W1[idx]); return; }
  idx -= 98304;
  if (idx < 65536) { W2bf[idx] = f2bf(W2[idx]); return; }
  idx -= 65536;
  if (idx < 16384) { zeros[idx] = 0.f; return; }
  idx -= 16384;
  // idx in [0,8192): (bg, q) source quad
  int bg = idx >> 8, q = idx & 255;
  int b = bg >> 4, g = bg & 15;
  const float* base = xyz2 + (size_t)b * 3 * GS_ + (size_t)g * S_ + q * 4;
  float4 X = *(const float4*)(base);
  float4 Y = *(const float4*)(base + GS_);
  float4 Z = *(const float4*)(base + 2 * GS_);
  float4 M;
  M.x = X.x*X.x + Y.x*Y.x + Z.x*Z.x;
  M.y = X.y*X.y + Y.y*Y.y + Z.y*Z.y;
  M.z = X.z*X.z + Y.z*Y.z + Z.z*Z.z;
  M.w = X.w*X.w + Y.w*Y.w + Z.w*Z.w;
  float4* dst = xyz2p + (size_t)idx * 4;
  dst[0] = X; dst[1] = Y; dst[2] = Z; dst[3] = M;
}

// ---------------- transpose points2 [c][s] f32 -> p2T [s][c] bf16 ----------------
__launch_bounds__(256)
__global__ void t2_kernel(const float* __restrict__ p2, u16* __restrict__ p2T)
{
  __shared__ float tl[64][65];
  int bx = blockIdx.x;
  int bg = bx >> 6, r = bx & 63;
  int ct = r >> 4, st = r & 15;
  int c0 = ct * 64, s0 = st * 64;
  int b = bg >> 4, g = bg & 15;
  int t = threadIdx.x, lane = t & 63, w = t >> 6;
  const float* src = p2 + (size_t)b * D2_ * GS_ + (size_t)g * S_ + s0 + lane;
  #pragma unroll
  for (int i = 0; i < 16; i++) {
    int row = w * 16 + i;
    tl[row][lane] = src[(size_t)(c0 + row) * GS_];
  }
  __syncthreads();
  int cp = t & 31, sr = t >> 5;
  #pragma unroll
  for (int i = 0; i < 8; i++) {
    int sl = sr * 8 + i;
    u32 v = (u32)f2bf(tl[2 * cp][sl]) | ((u32)f2bf(tl[2 * cp + 1][sl]) << 16);
    *(u32*)(p2T + (((size_t)bg * 1024 + s0 + sl) * 256 + c0 + 2 * cp)) = v;
  }
}

// ---------------- kNN: top-3 nearest sources per target ----------------
__launch_bounds__(256)
__global__ void knn_kernel(const float* __restrict__ xyz1, const float4* __restrict__ xyz2p,
                           float4* __restrict__ knnw, int4* __restrict__ knni)
{
  int bx = blockIdx.x;
  int bg = bx >> 4;
  int b = bg >> 4, g = bg & 15;
  int n = (bx & 15) * 256 + threadIdx.x;
  const float* x1b = xyz1 + (size_t)b * 3 * GN_ + (size_t)g * N_ + n;
  float x = x1b[0], y = x1b[GN_], z = x1b[2 * GN_];
  const float4* xp = xyz2p + (size_t)bg * 1024;
  float d0 = 3.4e38f, d1 = 3.4e38f, d2 = 3.4e38f;
  int i0 = 0, i1 = 0, i2 = 0;
  for (int q = 0; q < 256; q++) {
    float4 X = xp[q * 4 + 0], Y = xp[q * 4 + 1], Z = xp[q * 4 + 2], M = xp[q * 4 + 3];
    const float* Xa = (const float*)&X;
    const float* Ya = (const float*)&Y;
    const float* Za = (const float*)&Z;
    const float* Ma = (const float*)&M;
    #pragma unroll
    for (int u = 0; u < 4; u++) {
      float cr = x * Xa[u];
      cr = fmaf(y, Ya[u], cr);
      cr = fmaf(z, Za[u], cr);
      float d = fmaf(-2.f, cr, Ma[u]);
      int s = q * 4 + u;
      bool c2 = d < d2, c1 = d < d1, c0 = d < d0;
      d2 = c1 ? d1 : (c2 ? d : d2);  i2 = c1 ? i1 : (c2 ? s : i2);
      d1 = c0 ? d0 : (c1 ? d : d1);  i1 = c0 ? i0 : (c1 ? s : i1);
      d0 = c0 ? d : d0;              i0 = c0 ? s : i0;
    }
  }
  float m1 = x * x + y * y + z * z;
  float t0 = fmaxf(d0 + m1, 0.f), t1 = fmaxf(d1 + m1, 0.f), t2v = fmaxf(d2 + m1, 0.f);
  float w0 = 1.f / (t0 + 1e-8f);
  float w1 = 1.f / (t1 + 1e-8f);
  float w2 = 1.f / (t2v + 1e-8f);
  float inv = 1.f / (w0 + w1 + w2);
  size_t gi = (size_t)bg * 4096 + n;
  knnw[gi] = make_float4(w0 * inv, w1 * inv, w2 * inv, 0.f);
  knni[gi] = make_int4(i0, i1, i2, 0);
}

__device__ __forceinline__ float bfq(uint4 q, int i) {
  u32 w = (i < 2) ? ((i & 1) ? q.x >> 16 : (q.x & 0xffffu))
        : (i < 4) ? ((i & 1) ? q.y >> 16 : (q.y & 0xffffu))
        : (i < 6) ? ((i & 1) ? q.z >> 16 : (q.z & 0xffffu))
                  : ((i & 1) ? q.w >> 16 : (q.w & 0xffffu));
  return bf2f((u16)w);
}

// ---------------- GEMM1 fused: build B-tile (p1 transpose + 3NN interp) in LDS,
//                  Y1 = W1 @ B + b1, stats1, Y1 bf16 [n][256] coalesced ----------------
// LDS: Bs1 [64 rows][768B] XOR ((r&15)<<4)  @ 0      (48KB)
//      As1 [256 rows][64B] linear (m97)     @ 49152  (16KB)
//      Y1 out-tile [64 n][512B] XOR ((n&7)<<4) reuses @0 (32KB)
__launch_bounds__(256)
__global__ void gemm1_kernel(const u16* __restrict__ W1bf, const float* __restrict__ points1,
                             const u16* __restrict__ p2T,
                             const float4* __restrict__ knnw, const int4* __restrict__ knni,
                             const float* __restrict__ bias,
                             float* __restrict__ sumw, float* __restrict__ sqw,
                             u16* __restrict__ Y1)
{
  __shared__ __align__(16) char smem[65536];
  int bx = blockIdx.x;
  int bg = bx >> 6, nt = bx & 63;
  int b = bg >> 4, g = bg & 15;
  int n0 = nt * 64;
  int t = threadIdx.x;
  int wid = t >> 6, l = t & 63;
  int llo = l & 15, lhi = l >> 4;

  // ---- build Bs1: interp channels 128..383 ----
  {
    int half = l >> 5, cl = l & 31;
    size_t kbase = (size_t)bg * 4096 + n0;
    const u16* p2b = p2T + (size_t)bg * 1024 * 256;
    #pragma unroll
    for (int p = 0; p < 8; p++) {
      int r = wid * 16 + p * 2 + half;
      float4 wv = knnw[kbase + r];
      int4 iv = knni[kbase + r];
      uint4 q0 = *(const uint4*)(p2b + (size_t)iv.x * 256 + cl * 8);
      uint4 q1 = *(const uint4*)(p2b + (size_t)iv.y * 256 + cl * 8);
      uint4 q2 = *(const uint4*)(p2b + (size_t)iv.z * 256 + cl * 8);
      float av[8];
      #pragma unroll
      for (int i = 0; i < 8; i++)
        av[i] = wv.x * bfq(q0, i) + wv.y * bfq(q1, i) + wv.z * bfq(q2, i);
      uint4 o;
      o.x = (u32)f2bf(av[0]) | ((u32)f2bf(av[1]) << 16);
      o.y = (u32)f2bf(av[2]) | ((u32)f2bf(av[3]) << 16);
      o.z = (u32)f2bf(av[4]) | ((u32)f2bf(av[5]) << 16);
      o.w = (u32)f2bf(av[6]) | ((u32)f2bf(av[7]) << 16);
      int byteoff = r * 768 + ((256 + cl * 16) ^ ((r & 15) << 4));
      *(uint4*)(smem + byteoff) = o;
    }
  }
  // ---- build Bs1: p1 channels 0..127 (transpose) ----
  {
    const float* p1ch = points1 + ((size_t)b * 128 + wid * 32) * (size_t)GN_
                      + (size_t)g * N_ + n0 + l;
    #pragma unroll
    for (int cp = 0; cp < 16; cp++) {
      int c = wid * 32 + cp * 2;
      float v0 = p1ch[(size_t)(cp * 2) * GN_];
      float v1 = p1ch[(size_t)(cp * 2 + 1) * GN_];
      u32 pk = (u32)f2bf(v0) | ((u32)f2bf(v1) << 16);
      int byteoff = l * 768 + ((c * 2) ^ ((l & 15) << 4));
      *(u32*)(smem + byteoff) = pk;
    }
  }
  __syncthreads();

  f32x4 acc[4][4];
  #pragma unroll
  for (int i = 0; i < 4; i++)
    #pragma unroll
    for (int j = 0; j < 4; j++) acc[i][j] = (f32x4)0.f;

  u16* As = (u16*)(smem + 49152);
  for (int ks = 0; ks < 12; ks++) {
    #pragma unroll
    for (int q = 0; q < 4; q++) {
      int idx = (wid * 4 + q) * 64 + l;
      int row = idx >> 2, c16 = idx & 3;
      g2l16(W1bf + (size_t)row * 384 + ks * 32 + c16 * 8, As + (size_t)(wid * 4 + q) * 512);
    }
    __syncthreads();
    bf16x8 bfr[4];
    #pragma unroll
    for (int j = 0; j < 4; j++) {
      int rb = j * 16 + llo;
      bfr[j] = *(const bf16x8*)(smem + rb * 768 + ((ks * 64 + lhi * 16) ^ ((rb & 15) << 4)));
    }
    #pragma unroll
    for (int i = 0; i < 4; i++) {
      bf16x8 af = *(const bf16x8*)(smem + 49152 + (wid * 64 + i * 16 + llo) * 64 + lhi * 16);
      #pragma unroll
      for (int j = 0; j < 4; j++)
        acc[i][j] = __builtin_amdgcn_mfma_f32_16x16x32_bf16(af, bfr[j], acc[i][j], 0, 0, 0);
    }
    __syncthreads();
  }

  int m_base = wid * 64;
  // bias + per-channel stats
  #pragma unroll
  for (int i = 0; i < 4; i++) {
    #pragma unroll
    for (int r = 0; r < 4; r++) {
      int m = m_base + i * 16 + lhi * 4 + r;
      float bv = bias[m];
      float s = 0.f, ss = 0.f;
      #pragma unroll
      for (int j = 0; j < 4; j++) {
        float v = acc[i][j][r] + bv;
        acc[i][j][r] = v;
        s += v; ss += v * v;
      }
      #pragma unroll
      for (int off = 1; off < 16; off <<= 1) {
        s += __shfl_xor(s, off, 64);
        ss += __shfl_xor(ss, off, 64);
      }
      if (llo == 0) {
        atomicAdd(&sumw[g * 256 + m], s);
        atomicAdd(&sqw[g * 256 + m], ss);
      }
    }
  }
  // Y1 out-tile via LDS (coalesced global writes). Safe: last K-loop sync passed.
  #pragma unroll
  for (int i = 0; i < 4; i++)
    #pragma unroll
    for (int j = 0; j < 4; j++) {
      int n = j * 16 + llo, m = m_base + i * 16 + lhi * 4;
      uint2 pv;
      pv.x = (u32)f2bf(acc[i][j][0]) | ((u32)f2bf(acc[i][j][1]) << 16);
      pv.y = (u32)f2bf(acc[i][j][2]) | ((u32)f2bf(acc[i][j][3]) << 16);
      int byteoff = n * 512 + ((m * 2) ^ ((n & 7) << 4));
      *(uint2*)(smem + byteoff) = pv;
    }
  __syncthreads();
  {
    int rn = t >> 2, cq = t & 3;
    u16* yrow = Y1 + ((size_t)bg * 4096 + n0 + rn) * 256;
    #pragma unroll
    for (int u = 0; u < 8; u++) {
      int gq = u * 4 + cq;
      int byteoff = rn * 512 + ((gq * 16) ^ ((rn & 7) << 4));
      uint4 v = *(const uint4*)(smem + byteoff);
      *(uint4*)(yrow + gq * 8) = v;
    }
  }
}

// ---------------- BN finalize: (sum,sumsq) -> (scale,shift) ----------------
__global__ void bnfin_kernel(const float* __restrict__ sum, const float* __restrict__ sq,
                             const float* __restrict__ gamma, const float* __restrict__ beta,
                             float2* __restrict__ ss)
{
  int g = blockIdx.x, m = threadIdx.x;
  int i = g * 256 + m;
  float mean = sum[i] * (1.f / 8192.f);
  float var = sq[i] * (1.f / 8192.f) - mean * mean;
  var = fmaxf(var, 0.f);
  float rstd = rsqrtf(var + 1e-5f);
  float sc = gamma[m] * rstd;
  ss[i] = make_float2(sc, beta[m] - mean * sc);
}

// ---------------- GEMM2 fused: stage B from Y1 with BN1+ReLU in regs,
//                  Y2 = W2 @ relu(bn1(Y1)) + b2, stats2, Y2 bf16 in OUT layout ----------------
// LDS: As2 [256][64B] linear @0 (16KB) ; Bs2 [64][64B] linear @16384 (4KB)
//      params 256*float2 @20480 (2KB) ; Y2 out-tile [256 m][128B] XOR ((m&7)<<4) reuses @0 (32KB)
__launch_bounds__(256)
__global__ void gemm2_kernel(const u16* __restrict__ W2bf, const u16* __restrict__ Y1,
                             const float2* __restrict__ ss1, const float* __restrict__ bias,
                             float* __restrict__ sumw, float* __restrict__ sqw,
                             u16* __restrict__ Y2)
{
  __shared__ __align__(16) char smem[32768];
  int bx = blockIdx.x;
  int bg = bx >> 6, nt = bx & 63;
  int b = bg >> 4, g = bg & 15;
  int n0 = nt * 64;
  int t = threadIdx.x;
  int wid = t >> 6, l = t & 63;
  int llo = l & 15, lhi = l >> 4;

  if (t < 256) *(float2*)(smem + 20480 + t * 8) = ss1[g * 256 + t];
  __syncthreads();

  f32x4 acc[4][4];
  #pragma unroll
  for (int i = 0; i < 4; i++)
    #pragma unroll
    for (int j = 0; j < 4; j++) acc[i][j] = (f32x4)0.f;

  const u16* Ybase = Y1 + ((size_t)bg * 4096 + n0) * 256;
  u16* As = (u16*)smem;
  for (int ks = 0; ks < 8; ks++) {
    #pragma unroll
    for (int q = 0; q < 4; q++) {
      int idx = (wid * 4 + q) * 64 + l;
      int row = idx >> 2, c16 = idx & 3;
      g2l16(W2bf + (size_t)row * 256 + ks * 32 + c16 * 8, As + (size_t)(wid * 4 + q) * 512);
    }
    // reg-stage B with BN1+relu
    {
      int rn = t >> 2, qi = t & 3;
      uint4 yv = *(const uint4*)(Ybase + (size_t)rn * 256 + ks * 32 + qi * 8);
      const float2* pp = (const float2*)(smem + 20480 + (ks * 32 + qi * 8) * 8);
      const u32* yw = (const u32*)&yv;
      uint4 o;
      u32* ow = (u32*)&o;
      #pragma unroll
      for (int i2 = 0; i2 < 4; i2++) {
        float2 s0 = pp[2 * i2], s1 = pp[2 * i2 + 1];
        float a = fmaxf(fmaf(bf2f((u16)(yw[i2] & 0xffffu)), s0.x, s0.y), 0.f);
        float c = fmaxf(fmaf(bf2f((u16)(yw[i2] >> 16)), s1.x, s1.y), 0.f);
        ow[i2] = (u32)f2bf(a) | ((u32)f2bf(c) << 16);
      }
      *(uint4*)(smem + 16384 + rn * 64 + qi * 16) = o;
    }
    __syncthreads();
    bf16x8 bfr[4];
    #pragma unroll
    for (int j = 0; j < 4; j++)
      bfr[j] = *(const bf16x8*)(smem + 16384 + (j * 16 + llo) * 64 + lhi * 16);
    #pragma unroll
    for (int i = 0; i < 4; i++) {
      bf16x8 af = *(const bf16x8*)(smem + (wid * 64 + i * 16 + llo) * 64 + lhi * 16);
      #pragma unroll
      for (int j = 0; j < 4; j++)
        acc[i][j] = __builtin_amdgcn_mfma_f32_16x16x32_bf16(af, bfr[j], acc[i][j], 0, 0, 0);
    }
    __syncthreads();
  }

  int m_base = wid * 64;
  #pragma unroll
  for (int i = 0; i < 4; i++) {
    #pragma unroll
    for (int r = 0; r < 4; r++) {
      int m = m_base + i * 16 + lhi * 4 + r;
      float bv = bias[m];
      float s = 0.f, ss = 0.f;
      #pragma unroll
      for (int j = 0; j < 4; j++) {
        float v = acc[i][j][r] + bv;
        acc[i][j][r] = v;
        s += v; ss += v * v;
      }
      #pragma unroll
      for (int off = 1; off < 16; off <<= 1) {
        s += __shfl_xor(s, off, 64);
        ss += __shfl_xor(ss, off, 64);
      }
      if (llo == 0) {
        atomicAdd(&sumw[g * 256 + m], s);
        atomicAdd(&sqw[g * 256 + m], ss);
      }
    }
  }
  // Y2 out-tile [m][128B], scalar bf16 LDS writes, then coalesced global rows
  #pragma unroll
  for (int i = 0; i < 4; i++)
    #pragma unroll
    for (int j = 0; j < 4; j++) {
      int n = j * 16 + llo;
      #pragma unroll
      for (int r = 0; r < 4; r++) {
        int m = m_base + i * 16 + lhi * 4 + r;
        int byteoff = m * 128 + ((n * 2) ^ ((m & 7) << 4));
        *(u16*)(smem + byteoff) = f2bf(acc[i][j][r]);
      }
    }
  __syncthreads();
  {
    int cq = t & 3;
    #pragma unroll
    for (int pass = 0; pass < 4; pass++) {
      int m = pass * 64 + (t >> 2);
      u16* yrow = Y2 + ((size_t)b * 256 + m) * (size_t)GN_ + (size_t)g * N_ + n0;
      #pragma unroll
      for (int u = 0; u < 2; u++) {
        int gq = u * 4 + cq;
        int byteoff = m * 128 + ((gq * 16) ^ ((m & 7) << 4));
        uint4 v = *(const uint4*)(smem + byteoff);
        *(uint4*)(yrow + gq * 8) = v;
      }
    }
  }
}

// ---------------- BN apply 2: Out = relu(bn2(Y2)), bf16 -> f32 ----------------
__launch_bounds__(256)
__global__ void bnapply2_kernel(const u16* __restrict__ Y2, const float2* __restrict__ ss,
                                float* __restrict__ Out)
{
  int f8 = blockIdx.x * 256 + threadIdx.x;
  size_t base = (size_t)f8 * 8;
  int m = (int)((base >> 16) & 255);
  int g = (int)((base >> 12) & 15);
  float2 sc = ss[g * 256 + m];
  uint4 yv = *(const uint4*)(Y2 + base);
  const u32* yw = (const u32*)&yv;
  float4 a, b4;
  float* av = (float*)&a;
  float* bv = (float*)&b4;
  #pragma unroll
  for (int i = 0; i < 2; i++) {
    u32 w = yw[i];
    av[2 * i]     = fmaxf(fmaf(bf2f((u16)(w & 0xffffu)), sc.x, sc.y), 0.f);
    av[2 * i + 1] = fmaxf(fmaf(bf2f((u16)(w >> 16)),     sc.x, sc.y), 0.f);
  }
  #pragma unroll
  for (int i = 0; i < 2; i++) {
    u32 w = yw[2 + i];
    bv[2 * i]     = fmaxf(fmaf(bf2f((u16)(w & 0xffffu)), sc.x, sc.y), 0.f);
    bv[2 * i + 1] = fmaxf(fmaf(bf2f((u16)(w >> 16)),     sc.x, sc.y), 0.f);
  }
  *(float4*)(Out + base) = a;
  *(float4*)(Out + base + 4) = b4;
}

// ---------------- launch ----------------
extern "C" void kernel_launch(void* const* d_in, const int* in_sizes, int n_in,
                              void* d_out, int out_size, void* d_ws, size_t ws_size,
                              hipStream_t stream)
{
  (void)in_sizes; (void)n_in; (void)out_size; (void)ws_size;
  const float* xyz1    = (const float*)d_in[0];
  const float* points1 = (const float*)d_in[1];
  const float* xyz2    = (const float*)d_in[3];
  const float* points2 = (const float*)d_in[4];
  const float* W1      = (const float*)d_in[6];
  const float* b1      = (const float*)d_in[7];
  const float* gamma1  = (const float*)d_in[8];
  const float* beta1   = (const float*)d_in[9];
  const float* W2      = (const float*)d_in[10];
  const float* b2      = (const float*)d_in[11];
  const float* gamma2  = (const float*)d_in[12];
  const float* beta2   = (const float*)d_in[13];
  float* out = (float*)d_out;
  char* ws = (char*)d_ws;

  u16*    W1bf  = (u16*)(ws + OFF_W1BF);
  u16*    W2bf  = (u16*)(ws + OFF_W2BF);
  float4* xyz2p = (float4*)(ws + OFF_XYZ2P);
  float*  sum1  = (float*)(ws + OFF_SUM1);
  float*  sq1   = (float*)(ws + OFF_SQ1);
  float*  sum2  = (float*)(ws + OFF_SUM2);
  float*  sq2   = (float*)(ws + OFF_SQ2);
  float2* ss1   = (float2*)(ws + OFF_SS1);
  float2* ss2   = (float2*)(ws + OFF_SS2);
  float4* knnw  = (float4*)(ws + OFF_KNNW);
  int4*   knni  = (int4*)(ws + OFF_KNNI);
  u16*    p2T   = (u16*)(ws + OFF_P2T);
  u16*    Y2    = (u16*)(ws + OFF_Y2);
  u16*    Y1    = (u16*)(ws + OFF_Y1);

  prep_kernel<<<736, 256, 0, stream>>>(W1, W2, xyz2, W1bf, W2bf, xyz2p, sum1);
  t2_kernel<<<2048, 256, 0, stream>>>(points2, p2T);
  knn_kernel<<<512, 256, 0, stream>>>(xyz1, xyz2p, knnw, knni);
  gemm1_kernel<<<2048, 256, 0, stream>>>(W1bf, points1, p2T, knnw, knni, b1, sum1, sq1, Y1);
  bnfin_kernel<<<16, 256, 0, stream>>>(sum1, sq1, gamma1, beta1, ss1);
  gemm2_kernel<<<2048, 256, 0, stream>>>(W2bf, Y1, ss1, b2, sum2, sq2, Y2);
  bnfin_kernel<<<16, 256, 0, stream>>>(sum2, sq2, gamma2, beta2, ss2);
  bnapply2_kernel<<<16384, 256, 0, stream>>>(Y2, ss2, out);
}

// Round 3
// 335.890 us; speedup vs baseline: 1.4142x; 1.0149x over previous
//
#include <hip/hip_runtime.h>
#include <hip/hip_bf16.h>

// Problem constants
#define B_    2
#define G_    16
#define N_    4096
#define S_    1024
#define D1_   128
#define D2_   256
#define CIN_  384
#define BG_   32
#define GN_   65536
#define GS_   16384

typedef unsigned int u32;
typedef unsigned short u16;
typedef short bf16x8 __attribute__((ext_vector_type(8)));
typedef float f32x4 __attribute__((ext_vector_type(4)));

__device__ __forceinline__ float bf2f(u16 u) {
  union { float f; u32 v; } cv; cv.v = ((u32)u) << 16; return cv.f;
}
__device__ __forceinline__ u16 f2bf(float f) {
  union { __hip_bfloat16 h; u16 u; } cv; cv.h = __float2bfloat16(f); return cv.u;
}

// ---------------- workspace layout (bytes) ----------------
#define OFF_W1BF   0u
#define OFF_W2BF   196608u
#define OFF_XYZ2P  327680u
#define OFF_SUM1   851968u
#define OFF_SQ1    868352u
#define OFF_SUM2   884736u
#define OFF_SQ2    901120u
#define OFF_SS1    917504u
#define OFF_SS2    950272u
#define OFF_KNNW   983040u
#define OFF_KNNI   3080192u
#define OFF_P2T    5177344u
#define OFF_Y2     21954560u    // bf16 pre-BN2, OUT layout [b][m][gn]
#define OFF_Y1     122617856u   // bf16 pre-BN1, [bg*4096+n][256]

// ---------------- prep ----------------
__launch_bounds__(256)
__global__ void prep_kernel(const float* __restrict__ W1, const float* __restrict__ W2,
                            const float* __restrict__ xyz2,
                            u16* __restrict__ W1bf, u16* __restrict__ W2bf,
                            float4* __restrict__ xyz2p, float* __restrict__ zeros)
{
  int idx = blockIdx.x * 256 + threadIdx.x;
  if (idx < 98304) { W1bf[idx] = f2bf(W1[idx]); return; }
  idx -= 98304;
  if (idx < 65536) { W2bf[idx] = f2bf(W2[idx]); return; }
  idx -= 65536;
  if (idx < 16384) { zeros[idx] = 0.f; return; }
  idx -= 16384;
  int bg = idx >> 8, q = idx & 255;
  int b = bg >> 4, g = bg & 15;
  const float* base = xyz2 + (size_t)b * 3 * GS_ + (size_t)g * S_ + q * 4;
  float4 X = *(const float4*)(base);
  float4 Y = *(const float4*)(base + GS_);
  float4 Z = *(const float4*)(base + 2 * GS_);
  float4 M;
  M.x = X.x*X.x + Y.x*Y.x + Z.x*Z.x;
  M.y = X.y*X.y + Y.y*Y.y + Z.y*Z.y;
  M.z = X.z*X.z + Y.z*Y.z + Z.z*Z.z;
  M.w = X.w*X.w + Y.w*Y.w + Z.w*Z.w;
  float4* dst = xyz2p + (size_t)idx * 4;
  dst[0] = X; dst[1] = Y; dst[2] = Z; dst[3] = M;
}

// ---------------- transpose points2 -> p2T [s][256] bf16 ----------------
__launch_bounds__(256)
__global__ void t2_kernel(const float* __restrict__ p2, u16* __restrict__ p2T)
{
  __shared__ float tl[64][65];
  int bx = blockIdx.x;
  int bg = bx >> 6, r = bx & 63;
  int ct = r >> 4, st = r & 15;
  int c0 = ct * 64, s0 = st * 64;
  int b = bg >> 4, g = bg & 15;
  int t = threadIdx.x, lane = t & 63, w = t >> 6;
  const float* src = p2 + (size_t)b * D2_ * GS_ + (size_t)g * S_ + s0 + lane;
  #pragma unroll
  for (int i = 0; i < 16; i++) {
    int row = w * 16 + i;
    tl[row][lane] = src[(size_t)(c0 + row) * GS_];
  }
  __syncthreads();
  int cp = t & 31, sr = t >> 5;
  #pragma unroll
  for (int i = 0; i < 8; i++) {
    int sl = sr * 8 + i;
    u32 v = (u32)f2bf(tl[2 * cp][sl]) | ((u32)f2bf(tl[2 * cp + 1][sl]) << 16);
    *(u32*)(p2T + (((size_t)bg * 1024 + s0 + sl) * 256 + c0 + 2 * cp)) = v;
  }
}

// ---------------- kNN ----------------
__launch_bounds__(256)
__global__ void knn_kernel(const float* __restrict__ xyz1, const float4* __restrict__ xyz2p,
                           float4* __restrict__ knnw, int4* __restrict__ knni)
{
  int bx = blockIdx.x;
  int bg = bx >> 4;
  int b = bg >> 4, g = bg & 15;
  int n = (bx & 15) * 256 + threadIdx.x;
  const float* x1b = xyz1 + (size_t)b * 3 * GN_ + (size_t)g * N_ + n;
  float x = x1b[0], y = x1b[GN_], z = x1b[2 * GN_];
  const float4* xp = xyz2p + (size_t)bg * 1024;
  float d0 = 3.4e38f, d1 = 3.4e38f, d2 = 3.4e38f;
  int i0 = 0, i1 = 0, i2 = 0;
  for (int q = 0; q < 256; q++) {
    float4 X = xp[q * 4 + 0], Y = xp[q * 4 + 1], Z = xp[q * 4 + 2], M = xp[q * 4 + 3];
    const float* Xa = (const float*)&X;
    const float* Ya = (const float*)&Y;
    const float* Za = (const float*)&Z;
    const float* Ma = (const float*)&M;
    #pragma unroll
    for (int u = 0; u < 4; u++) {
      float cr = x * Xa[u];
      cr = fmaf(y, Ya[u], cr);
      cr = fmaf(z, Za[u], cr);
      float d = fmaf(-2.f, cr, Ma[u]);
      int s = q * 4 + u;
      bool c2 = d < d2, c1 = d < d1, c0 = d < d0;
      d2 = c1 ? d1 : (c2 ? d : d2);  i2 = c1 ? i1 : (c2 ? s : i2);
      d1 = c0 ? d0 : (c1 ? d : d1);  i1 = c0 ? i0 : (c1 ? s : i1);
      d0 = c0 ? d : d0;              i0 = c0 ? s : i0;
    }
  }
  float m1 = x * x + y * y + z * z;
  float t0 = fmaxf(d0 + m1, 0.f), t1 = fmaxf(d1 + m1, 0.f), t2v = fmaxf(d2 + m1, 0.f);
  float w0 = 1.f / (t0 + 1e-8f);
  float w1 = 1.f / (t1 + 1e-8f);
  float w2 = 1.f / (t2v + 1e-8f);
  float inv = 1.f / (w0 + w1 + w2);
  size_t gi = (size_t)bg * 4096 + n;
  knnw[gi] = make_float4(w0 * inv, w1 * inv, w2 * inv, 0.f);
  knni[gi] = make_int4(i0, i1, i2, 0);
}

__device__ __forceinline__ float bfq(uint4 q, int i) {
  u32 w = (i < 2) ? ((i & 1) ? q.x >> 16 : (q.x & 0xffffu))
        : (i < 4) ? ((i & 1) ? q.y >> 16 : (q.y & 0xffffu))
        : (i < 6) ? ((i & 1) ? q.z >> 16 : (q.z & 0xffffu))
                  : ((i & 1) ? q.w >> 16 : (q.w & 0xffffu));
  return bf2f((u16)w);
}

// ================= GEMM1: A(W1) in regs, B built per 64n-tile (dbuf), full-K =================
// grid: 32 bg * 2 mh * 16 ng. Block: M=128, N=256 (4 tiles of 64).
// LDS: Bbuf0 @0 (49152 = 64 rows * 768B, XOR ((r&15)<<4) on 16B slots)
//      Bbuf1 @49152 ; outLDS @98304 (64n * 256B, XOR ((n&7)<<4)) ; total 114688
__launch_bounds__(256, 1)
__global__ void gemm1_kernel(const u16* __restrict__ W1bf, const float* __restrict__ points1,
                             const u16* __restrict__ p2T,
                             const float4* __restrict__ knnw, const int4* __restrict__ knni,
                             const float* __restrict__ bias,
                             float* __restrict__ sumw, float* __restrict__ sqw,
                             u16* __restrict__ Y1)
{
  __shared__ __align__(16) char smem[114688];
  int bx = blockIdx.x;
  int bg = bx >> 5, mh = (bx >> 4) & 1, ng = bx & 15;
  int b = bg >> 4, g = bg & 15;
  int nbase = ng * 256;
  int t = threadIdx.x, wid = t >> 6, l = t & 63;
  int llo = l & 15, lhi = l >> 4;
  int mw = mh * 128 + wid * 32;

  // A fragments in registers (once)
  bf16x8 af[2][12];
  #pragma unroll
  for (int i = 0; i < 2; i++)
    #pragma unroll
    for (int ks = 0; ks < 12; ks++)
      af[i][ks] = *(const bf16x8*)(W1bf + (size_t)(mw + i * 16 + llo) * 384 + ks * 32 + lhi * 8);

  float bv[2][4];
  #pragma unroll
  for (int i = 0; i < 2; i++)
    #pragma unroll
    for (int r = 0; r < 4; r++)
      bv[i][r] = bias[mw + i * 16 + lhi * 4 + r];

  // stage registers (live across MFMA - T14)
  uint4 q0[8], q1[8], q2[8];
  float4 wv8[8];
  float p1v[32];
  int half = l >> 5, cl = l & 31;
  const u16* p2b = p2T + (size_t)bg * 1024 * 256;

  auto issue = [&](int tile) {
    size_t kb = (size_t)bg * 4096 + nbase + tile * 64;
    #pragma unroll
    for (int p = 0; p < 8; p++) {
      int r = wid * 16 + p * 2 + half;
      wv8[p] = knnw[kb + r];
      int4 iv = knni[kb + r];
      q0[p] = *(const uint4*)(p2b + (size_t)iv.x * 256 + cl * 8);
      q1[p] = *(const uint4*)(p2b + (size_t)iv.y * 256 + cl * 8);
      q2[p] = *(const uint4*)(p2b + (size_t)iv.z * 256 + cl * 8);
    }
    const float* p1c = points1 + (size_t)b * 128 * GN_ + (size_t)g * N_ + nbase + tile * 64 + l;
    #pragma unroll
    for (int c = 0; c < 32; c++)
      p1v[c] = p1c[(size_t)(wid * 32 + c) * GN_];
  };

  auto writeB = [&](int tile) {
    char* buf = smem + (tile & 1) * 49152;
    #pragma unroll
    for (int p = 0; p < 8; p++) {
      int r = wid * 16 + p * 2 + half;
      float4 w4 = wv8[p];
      float av[8];
      #pragma unroll
      for (int i = 0; i < 8; i++)
        av[i] = w4.x * bfq(q0[p], i) + w4.y * bfq(q1[p], i) + w4.z * bfq(q2[p], i);
      uint4 o;
      o.x = (u32)f2bf(av[0]) | ((u32)f2bf(av[1]) << 16);
      o.y = (u32)f2bf(av[2]) | ((u32)f2bf(av[3]) << 16);
      o.z = (u32)f2bf(av[4]) | ((u32)f2bf(av[5]) << 16);
      o.w = (u32)f2bf(av[6]) | ((u32)f2bf(av[7]) << 16);
      int byteoff = r * 768 + ((256 + cl * 16) ^ ((r & 15) << 4));
      *(uint4*)(buf + byteoff) = o;
    }
    #pragma unroll
    for (int cp = 0; cp < 16; cp++) {
      int c = wid * 32 + cp * 2;
      u32 pk = (u32)f2bf(p1v[cp * 2]) | ((u32)f2bf(p1v[cp * 2 + 1]) << 16);
      int byteoff = l * 768 + ((c * 2) ^ ((l & 15) << 4));
      *(u32*)(buf + byteoff) = pk;
    }
  };

  float st[2][4], sq2r[2][4];
  #pragma unroll
  for (int i = 0; i < 2; i++)
    #pragma unroll
    for (int r = 0; r < 4; r++) { st[i][r] = 0.f; sq2r[i][r] = 0.f; }

  issue(0);
  writeB(0);
  issue(1);

  for (int t4 = 0; t4 < 4; t4++) {
    __syncthreads();   // B[t4] ready
    const char* buf = smem + (t4 & 1) * 49152;
    f32x4 acc[2][4];
    #pragma unroll
    for (int i = 0; i < 2; i++)
      #pragma unroll
      for (int j = 0; j < 4; j++) acc[i][j] = (f32x4)0.f;
    #pragma unroll
    for (int ks = 0; ks < 12; ks++) {
      bf16x8 bfr[4];
      #pragma unroll
      for (int j = 0; j < 4; j++) {
        int rb = j * 16 + llo;
        bfr[j] = *(const bf16x8*)(buf + rb * 768 + ((ks * 64 + lhi * 16) ^ ((rb & 15) << 4)));
      }
      #pragma unroll
      for (int i = 0; i < 2; i++)
        #pragma unroll
        for (int j = 0; j < 4; j++)
          acc[i][j] = __builtin_amdgcn_mfma_f32_16x16x32_bf16(af[i][ks], bfr[j], acc[i][j], 0, 0, 0);
    }
    if (t4 < 3) writeB(t4 + 1);
    // epilogue: bias, stats, outLDS
    #pragma unroll
    for (int i = 0; i < 2; i++) {
      int mloc = wid * 32 + i * 16 + lhi * 4;
      int slot = mloc >> 3, off8 = (mloc & 7) * 2;
      #pragma unroll
      for (int j = 0; j < 4; j++) {
        int n = j * 16 + llo;
        float v0 = acc[i][j][0] + bv[i][0];
        float v1 = acc[i][j][1] + bv[i][1];
        float v2 = acc[i][j][2] + bv[i][2];
        float v3 = acc[i][j][3] + bv[i][3];
        st[i][0] += v0; sq2r[i][0] += v0 * v0;
        st[i][1] += v1; sq2r[i][1] += v1 * v1;
        st[i][2] += v2; sq2r[i][2] += v2 * v2;
        st[i][3] += v3; sq2r[i][3] += v3 * v3;
        int base = n * 256 + ((slot * 16) ^ ((n & 7) << 4)) + off8;
        *(u32*)(smem + 98304 + base) = (u32)f2bf(v0) | ((u32)f2bf(v1) << 16);
        *(u32*)(smem + 98304 + base + 4) = (u32)f2bf(v2) | ((u32)f2bf(v3) << 16);
      }
    }
    __syncthreads();   // outLDS ready; B[(t4+1)&1] written
    {
      int rn = t >> 2, cpos = t & 3;
      u16* yrow = Y1 + ((size_t)bg * 4096 + nbase + t4 * 64 + rn) * 256 + mh * 128;
      #pragma unroll
      for (int u = 0; u < 4; u++) {
        int s = cpos + u * 4;
        uint4 v = *(const uint4*)(smem + 98304 + rn * 256 + ((s * 16) ^ ((rn & 7) << 4)));
        *(uint4*)(yrow + s * 8) = v;
      }
    }
    if (t4 < 2) issue(t4 + 2);
  }

  // stats reduce + atomics
  #pragma unroll
  for (int i = 0; i < 2; i++)
    #pragma unroll
    for (int r = 0; r < 4; r++) {
      float s = st[i][r], ss = sq2r[i][r];
      #pragma unroll
      for (int off = 1; off < 16; off <<= 1) {
        s += __shfl_xor(s, off, 64);
        ss += __shfl_xor(ss, off, 64);
      }
      if (llo == 0) {
        int m = mw + i * 16 + lhi * 4 + r;
        atomicAdd(&sumw[g * 256 + m], s);
        atomicAdd(&sqw[g * 256 + m], ss);
      }
    }
}

// ---------------- BN finalize ----------------
__global__ void bnfin_kernel(const float* __restrict__ sum, const float* __restrict__ sq,
                             const float* __restrict__ gamma, const float* __restrict__ beta,
                             float2* __restrict__ ss)
{
  int g = blockIdx.x, m = threadIdx.x;
  int i = g * 256 + m;
  float mean = sum[i] * (1.f / 8192.f);
  float var = sq[i] * (1.f / 8192.f) - mean * mean;
  var = fmaxf(var, 0.f);
  float rstd = rsqrtf(var + 1e-5f);
  float sc = gamma[m] * rstd;
  ss[i] = make_float2(sc, beta[m] - mean * sc);
}

// ================= GEMM2: A(W2) in regs, B = relu(bn1(Y1)) staged per tile (single buf) ======
// grid: 32 bg * 2 mh * 16 ng. Block: M=128, N=256 (4 tiles of 64).
// LDS: B2 @0 (32768 = 64 rows * 512B, XOR ((r&15)<<4)); outLDS @32768 (128m*128B, XOR ((m&7)<<4));
//      ss params @49152 (2048); total 51200 -> 2-3 blocks/CU
__launch_bounds__(256, 2)
__global__ void gemm2_kernel(const u16* __restrict__ W2bf, const u16* __restrict__ Y1,
                             const float2* __restrict__ ss1, const float* __restrict__ bias,
                             float* __restrict__ sumw, float* __restrict__ sqw,
                             u16* __restrict__ Y2)
{
  __shared__ __align__(16) char smem[51200];
  int bx = blockIdx.x;
  int bg = bx >> 5, mh = (bx >> 4) & 1, ng = bx & 15;
  int b = bg >> 4, g = bg & 15;
  int nbase = ng * 256;
  int t = threadIdx.x, wid = t >> 6, l = t & 63;
  int llo = l & 15, lhi = l >> 4;
  int mw = mh * 128 + wid * 32;

  bf16x8 af[2][8];
  #pragma unroll
  for (int i = 0; i < 2; i++)
    #pragma unroll
    for (int ks = 0; ks < 8; ks++)
      af[i][ks] = *(const bf16x8*)(W2bf + (size_t)(mw + i * 16 + llo) * 256 + ks * 32 + lhi * 8);

  float bv[2][4];
  #pragma unroll
  for (int i = 0; i < 2; i++)
    #pragma unroll
    for (int r = 0; r < 4; r++)
      bv[i][r] = bias[mw + i * 16 + lhi * 4 + r];

  if (t < 256) *(float2*)(smem + 49152 + t * 8) = ss1[g * 256 + t];

  int rn = t >> 2, qq = t & 3;
  uint4 sreg[8];
  auto issue = [&](int tile) {
    const u16* yrow = Y1 + ((size_t)bg * 4096 + nbase + tile * 64 + rn) * 256 + qq * 64;
    #pragma unroll
    for (int u = 0; u < 8; u++)
      sreg[u] = *(const uint4*)(yrow + u * 8);
  };
  auto writeB = [&](int tile) {
    const float2* pp = (const float2*)(smem + 49152);
    #pragma unroll
    for (int u = 0; u < 8; u++) {
      int ch0 = qq * 64 + u * 8;
      const u32* yw = (const u32*)&sreg[u];
      uint4 o;
      u32* ow = (u32*)&o;
      #pragma unroll
      for (int i2 = 0; i2 < 4; i2++) {
        float2 s0 = pp[ch0 + 2 * i2], s1 = pp[ch0 + 2 * i2 + 1];
        float a = fmaxf(fmaf(bf2f((u16)(yw[i2] & 0xffffu)), s0.x, s0.y), 0.f);
        float c = fmaxf(fmaf(bf2f((u16)(yw[i2] >> 16)), s1.x, s1.y), 0.f);
        ow[i2] = (u32)f2bf(a) | ((u32)f2bf(c) << 16);
      }
      int slot = qq * 8 + u;
      *(uint4*)(smem + rn * 512 + ((slot * 16) ^ ((rn & 15) << 4))) = o;
    }
  };

  float st[2][4], sq2r[2][4];
  #pragma unroll
  for (int i = 0; i < 2; i++)
    #pragma unroll
    for (int r = 0; r < 4; r++) { st[i][r] = 0.f; sq2r[i][r] = 0.f; }

  issue(0);
  __syncthreads();   // ss params ready
  writeB(0);
  issue(1);

  for (int t4 = 0; t4 < 4; t4++) {
    __syncthreads();   // B2 ready
    f32x4 acc[2][4];
    #pragma unroll
    for (int i = 0; i < 2; i++)
      #pragma unroll
      for (int j = 0; j < 4; j++) acc[i][j] = (f32x4)0.f;
    #pragma unroll
    for (int ks = 0; ks < 8; ks++) {
      bf16x8 bfr[4];
      #pragma unroll
      for (int j = 0; j < 4; j++) {
        int rb = j * 16 + llo;
        bfr[j] = *(const bf16x8*)(smem + rb * 512 + ((ks * 64 + lhi * 16) ^ ((rb & 15) << 4)));
      }
      #pragma unroll
      for (int i = 0; i < 2; i++)
        #pragma unroll
        for (int j = 0; j < 4; j++)
          acc[i][j] = __builtin_amdgcn_mfma_f32_16x16x32_bf16(af[i][ks], bfr[j], acc[i][j], 0, 0, 0);
    }
    // epilogue: bias, stats, m-major outLDS
    #pragma unroll
    for (int i = 0; i < 2; i++) {
      #pragma unroll
      for (int j = 0; j < 4; j++) {
        int n = j * 16 + llo;
        int slotn = n >> 3, offn = (n & 7) * 2;
        #pragma unroll
        for (int r = 0; r < 4; r++) {
          float v = acc[i][j][r] + bv[i][r];
          st[i][r] += v; sq2r[i][r] += v * v;
          int mr = wid * 32 + i * 16 + lhi * 4 + r;
          *(u16*)(smem + 32768 + mr * 128 + ((slotn * 16) ^ ((mr & 7) << 4)) + offn) = f2bf(v);
        }
      }
    }
    __syncthreads();   // outLDS ready; all waves done reading B2
    {
      int mr = t >> 1, hh = t & 1;
      u16* yrow = Y2 + ((size_t)b * 256 + mh * 128 + mr) * (size_t)GN_
                + (size_t)g * N_ + nbase + t4 * 64;
      #pragma unroll
      for (int u = 0; u < 4; u++) {
        int s = hh + u * 2;
        uint4 v = *(const uint4*)(smem + 32768 + mr * 128 + ((s * 16) ^ ((mr & 7) << 4)));
        *(uint4*)(yrow + s * 8) = v;
      }
    }
    if (t4 < 3) writeB(t4 + 1);
    if (t4 < 2) issue(t4 + 2);
  }

  #pragma unroll
  for (int i = 0; i < 2; i++)
    #pragma unroll
    for (int r = 0; r < 4; r++) {
      float s = st[i][r], ss = sq2r[i][r];
      #pragma unroll
      for (int off = 1; off < 16; off <<= 1) {
        s += __shfl_xor(s, off, 64);
        ss += __shfl_xor(ss, off, 64);
      }
      if (llo == 0) {
        int m = mw + i * 16 + lhi * 4 + r;
        atomicAdd(&sumw[g * 256 + m], s);
        atomicAdd(&sqw[g * 256 + m], ss);
      }
    }
}

// ---------------- BN apply 2: Out = relu(bn2(Y2)), bf16 -> f32 ----------------
__launch_bounds__(256)
__global__ void bnapply2_kernel(const u16* __restrict__ Y2, const float2* __restrict__ ss,
                                float* __restrict__ Out)
{
  int f8 = blockIdx.x * 256 + threadIdx.x;
  size_t base = (size_t)f8 * 8;
  int m = (int)((base >> 16) & 255);
  int g = (int)((base >> 12) & 15);
  float2 sc = ss[g * 256 + m];
  uint4 yv = *(const uint4*)(Y2 + base);
  const u32* yw = (const u32*)&yv;
  float4 a, b4;
  float* av = (float*)&a;
  float* bvv = (float*)&b4;
  #pragma unroll
  for (int i = 0; i < 2; i++) {
    u32 w = yw[i];
    av[2 * i]     = fmaxf(fmaf(bf2f((u16)(w & 0xffffu)), sc.x, sc.y), 0.f);
    av[2 * i + 1] = fmaxf(fmaf(bf2f((u16)(w >> 16)),     sc.x, sc.y), 0.f);
  }
  #pragma unroll
  for (int i = 0; i < 2; i++) {
    u32 w = yw[2 + i];
    bvv[2 * i]     = fmaxf(fmaf(bf2f((u16)(w & 0xffffu)), sc.x, sc.y), 0.f);
    bvv[2 * i + 1] = fmaxf(fmaf(bf2f((u16)(w >> 16)),     sc.x, sc.y), 0.f);
  }
  *(float4*)(Out + base) = a;
  *(float4*)(Out + base + 4) = b4;
}

// ---------------- launch ----------------
extern "C" void kernel_launch(void* const* d_in, const int* in_sizes, int n_in,
                              void* d_out, int out_size, void* d_ws, size_t ws_size,
                              hipStream_t stream)
{
  (void)in_sizes; (void)n_in; (void)out_size; (void)ws_size;
  const float* xyz1    = (const float*)d_in[0];
  const float* points1 = (const float*)d_in[1];
  const float* xyz2    = (const float*)d_in[3];
  const float* points2 = (const float*)d_in[4];
  const float* W1      = (const float*)d_in[6];
  const float* b1      = (const float*)d_in[7];
  const float* gamma1  = (const float*)d_in[8];
  const float* beta1   = (const float*)d_in[9];
  const float* W2      = (const float*)d_in[10];
  const float* b2      = (const float*)d_in[11];
  const float* gamma2  = (const float*)d_in[12];
  const float* beta2   = (const float*)d_in[13];
  float* out = (float*)d_out;
  char* ws = (char*)d_ws;

  u16*    W1bf  = (u16*)(ws + OFF_W1BF);
  u16*    W2bf  = (u16*)(ws + OFF_W2BF);
  float4* xyz2p = (float4*)(ws + OFF_XYZ2P);
  float*  sum1  = (float*)(ws + OFF_SUM1);
  float*  sq1   = (float*)(ws + OFF_SQ1);
  float*  sum2  = (float*)(ws + OFF_SUM2);
  float*  sq2   = (float*)(ws + OFF_SQ2);
  float2* ss1   = (float2*)(ws + OFF_SS1);
  float2* ss2   = (float2*)(ws + OFF_SS2);
  float4* knnw  = (float4*)(ws + OFF_KNNW);
  int4*   knni  = (int4*)(ws + OFF_KNNI);
  u16*    p2T   = (u16*)(ws + OFF_P2T);
  u16*    Y2    = (u16*)(ws + OFF_Y2);
  u16*    Y1    = (u16*)(ws + OFF_Y1);

  prep_kernel<<<736, 256, 0, stream>>>(W1, W2, xyz2, W1bf, W2bf, xyz2p, sum1);
  t2_kernel<<<2048, 256, 0, stream>>>(points2, p2T);
  knn_kernel<<<512, 256, 0, stream>>>(xyz1, xyz2p, knnw, knni);
  gemm1_kernel<<<1024, 256, 0, stream>>>(W1bf, points1, p2T, knnw, knni, b1, sum1, sq1, Y1);
  bnfin_kernel<<<16, 256, 0, stream>>>(sum1, sq1, gamma1, beta1, ss1);
  gemm2_kernel<<<1024, 256, 0, stream>>>(W2bf, Y1, ss1, b2, sum2, sq2, Y2);
  bnfin_kernel<<<16, 256, 0, stream>>>(sum2, sq2, gamma2, beta2, ss2);
  bnapply2_kernel<<<16384, 256, 0, stream>>>(Y2, ss2, out);
}